// Round 14
// baseline (9475.280 us; speedup 1.0000x reference)
//
#include <hip/hip_runtime.h>

// SimpleLSTM B=256, T=512, I=3, H=512. out = fc(h_T).
// R14 = R13 (known-pass 1.93ms, absmax 2.4e-4) with ONE change:
// A-fragment loads are now PLAIN CACHED (L1/L2) instead of sc0sc1-bypass,
// made correct by an explicit agent-scope ACQUIRE fence at the top of each
// step (lowers to the L1/L2 invalidate). Theory: sc0sc1 reads are uncached
// LLC requests; 8MB/step burst at UC service BW ~= the whole step time.
// Cached reads let the ~4 same-group wgs per XCD share the 32KB A-tile via
// L2. h-stores stay sc0sc1 write-through (LLC-visible before flag, ordering
// unchanged). R2's mistake (full wbl2 writeback storm) is NOT repeated:
// acquire-only fence. Stale-read failure = finite absmax jump -> revert.

#define Hh   512
#define Bsz  256
#define Tt   512

#define MB   32
#define HS   16
#define NROW 64
#define NTHR 512
#define NWG  256

typedef float    f32x4 __attribute__((ext_vector_type(4)));
typedef _Float16 f16x8 __attribute__((ext_vector_type(8)));
typedef unsigned long long u64;

#define PLANE_SZ (2 * Bsz * Hh * 2)          // 512 KB: [2][256][512] f16
#define BAR_OFF  PLANE_SZ
#define CTRL_UINTS 512                       // [256 + bb*32 + hb] = arrival flags

__device__ __forceinline__ float sigm(float v)  { return 1.0f / (1.0f + __expf(-v)); }
__device__ __forceinline__ float tanhx(float v) { return 2.0f / (1.0f + __expf(-2.0f * v)) - 1.0f; }

__device__ __forceinline__ ushort f2h(float f) {      // RNE f32 -> f16 bits
  return __builtin_bit_cast(ushort, (_Float16)f);
}
__device__ __forceinline__ float h2f(ushort u) {
  return (float)__builtin_bit_cast(_Float16, u);
}

// Plain cached 16B load (L1/L2). Freshness guaranteed by the per-step
// agent-acquire fence. Batched issue + single vmcnt drain as before.
#define GLOAD(dst, base, imm)                                            \
  asm volatile("global_load_dwordx4 %0, %1, off offset:%c2"              \
               : "=v"(dst) : "v"(base), "i"(imm))

// Flag barrier at LLC (R12-validated). Arrival: tid0 stores monotone target
// to own flag after vmcnt drain + syncthreads. Exit: wave0 polls all 32
// flags (poll first, sleep on miss), __all releases, syncthreads broadcasts.
__device__ __forceinline__ void group_barrier(unsigned* flags, int hb, int tid, unsigned target) {
  asm volatile("s_waitcnt vmcnt(0)" ::: "memory");
  __syncthreads();
  if (tid == 0) {
    unsigned v = target;
    asm volatile("global_store_dword %0, %1, off sc0 sc1"
                 :: "v"(flags + hb), "v"(v) : "memory");
  }
  if (tid < 64) {
    const unsigned* fp = flags + (tid & 31);
    unsigned v;
    for (;;) {
      asm volatile("global_load_dword %0, %1, off sc0 sc1\n\t"
                   "s_waitcnt vmcnt(0)" : "=v"(v) : "v"(fp) : "memory");
      if (__all((int)(v >= target))) break;
      __builtin_amdgcn_s_sleep(1);
    }
  }
  __syncthreads();
}

__global__ void init_ws(unsigned* ctrl) {
  ctrl[threadIdx.x] = 0u;
}

__global__ __launch_bounds__(NTHR, 2)
void lstm_kernel(const float* __restrict__ x,   const float* __restrict__ Wih,
                 const float* __restrict__ Whh, const float* __restrict__ bih,
                 const float* __restrict__ bhh, const float* __restrict__ fcw,
                 const float* __restrict__ fcb, float* __restrict__ out,
                 char* __restrict__ ws)
{
  const int tid = threadIdx.x;
  const int wg  = blockIdx.x;
  const int bb  = wg & 7;
  const int hb  = wg >> 3;
  const int j0  = hb * HS;
  const int b0  = bb * MB;

  ushort*   hpl   = (ushort*)ws;             // fp16 h planes [2][256][512]
  unsigned* flags = (unsigned*)(ws + BAR_OFF) + 256 + bb * 32;

  // Fragment-linear W (f16 split): whiF[((q*16 + kblk)*64 + lane)*8 + e]
  __shared__ ushort whiF[4 * 16 * 64 * 8];   // 64 KB: f16(W)
  __shared__ ushort wloF[4 * 16 * 64 * 8];   // 64 KB: f16((W - hi) * 1024)
  __shared__ float  gates2[2][4][MB][20];    // two-stage K-partials, pad 20
  __shared__ float  wih_s[NROW][3];
  __shared__ float  bsum[NROW];
  __shared__ float  xs[MB][3];

  if (tid < NROW) {
    int qq = tid >> 4, jj = tid & 15;
    int grow = qq * Hh + j0 + jj;
    wih_s[tid][0] = Wih[grow * 3 + 0];
    wih_s[tid][1] = Wih[grow * 3 + 1];
    wih_s[tid][2] = Wih[grow * 3 + 2];
    bsum[tid] = bih[grow] + bhh[grow];
  }

  for (int idx = tid; idx < NROW * 64; idx += NTHR) {
    int row = idx >> 6, seg = idx & 63;
    int qq = row >> 4, jj = row & 15;
    const float* src = Whh + (size_t)(qq * Hh + j0 + jj) * Hh + seg * 8;
    float4 w0 = *(const float4*)(src);
    float4 w1 = *(const float4*)(src + 4);
    float wv[8] = {w0.x, w0.y, w0.z, w0.w, w1.x, w1.y, w1.z, w1.w};
    unsigned uhi[4], ulo[4];
    #pragma unroll
    for (int p = 0; p < 4; ++p) {
      ushort h0 = f2h(wv[2*p]);
      ushort h1 = f2h(wv[2*p+1]);
      ushort l0 = f2h((wv[2*p]   - h2f(h0)) * 1024.0f);
      ushort l1 = f2h((wv[2*p+1] - h2f(h1)) * 1024.0f);
      uhi[p] = (unsigned)h0 | ((unsigned)h1 << 16);
      ulo[p] = (unsigned)l0 | ((unsigned)l1 << 16);
    }
    int kblk = seg >> 2, lkk = seg & 3;
    int dst = ((qq * 16 + kblk) * 64 + lkk * 16 + jj) * 8;
    *(uint4*)&whiF[dst] = make_uint4(uhi[0], uhi[1], uhi[2], uhi[3]);
    *(uint4*)&wloF[dst] = make_uint4(ulo[0], ulo[1], ulo[2], ulo[3]);
  }

  // ---- zero h_0 slice (buffer 0) ----
  {
    int b = tid >> 4, jj = tid & 15;
    size_t o = (size_t)(b0 + b) * Hh + j0 + jj;
    __hip_atomic_store(&hpl[o], (ushort)0, __ATOMIC_RELAXED, __HIP_MEMORY_SCOPE_AGENT);
  }
  group_barrier(flags, hb, tid, 1u);

  const int l   = tid & 63;
  const int wid = tid >> 6;
  const int m   = wid >> 2;            // batch half (0..1)
  const int ks  = wid & 3;             // K quarter (0..3)
  const int lm  = l & 15;
  const int lk  = l >> 4;              // 0..3

  const size_t aoff  = (size_t)(b0 + m * 16 + lm) * Hh + ks * 128 + lk * 8;
  const int    wq0   = ks * 2048 + l * 8;   // + q*8192 + u*512 (ushort idx)

  const int cb = tid >> 4;
  const int cj = tid & 15;
  float c_state = 0.0f;

  int cur = 0;
  for (int t = 0; t < Tt; ++t) {
    // ---- acquire: invalidate L1/L2 so cached h reads see this step's data ----
    __builtin_amdgcn_fence(__ATOMIC_ACQUIRE, "agent");

    if (tid < MB * 3) {
      int b = tid / 3, ii = tid - b * 3;
      xs[b][ii] = x[(size_t)(b0 + b) * (Tt * 3) + t * 3 + ii];
    }

    // ---- 4 pipelined A loads (distinct K-quarter, fp16, CACHED) ----
    const char* pH = (const char*)(hpl + (size_t)cur * Bsz * Hh + aoff);
    f32x4 AH[4];
    GLOAD(AH[0], pH, 0);  GLOAD(AH[1], pH, 64);  GLOAD(AH[2], pH, 128); GLOAD(AH[3], pH, 192);
    asm volatile("s_waitcnt vmcnt(0)" ::: "memory");
    __builtin_amdgcn_sched_barrier(0);

    // ---- 4 quadrants x 4 k-blocks x 2 terms (hi, scaled lo) = 32 MFMAs ----
    f32x4 h0 = {0,0,0,0}, h1 = {0,0,0,0}, h2 = {0,0,0,0}, h3 = {0,0,0,0};
    f32x4 l0 = {0,0,0,0}, l1 = {0,0,0,0}, l2 = {0,0,0,0}, l3 = {0,0,0,0};
    #pragma unroll
    for (int u = 0; u < 4; ++u) {
      f16x8 ah = __builtin_bit_cast(f16x8, AH[u]);
      const int fo = wq0 + u * 512;
      {
        f16x8 bh = *(const f16x8*)&whiF[0 * 8192 + fo];
        f16x8 bl = *(const f16x8*)&wloF[0 * 8192 + fo];
        h0 = __builtin_amdgcn_mfma_f32_16x16x32_f16(ah, bh, h0, 0, 0, 0);
        l0 = __builtin_amdgcn_mfma_f32_16x16x32_f16(ah, bl, l0, 0, 0, 0);
      }
      {
        f16x8 bh = *(const f16x8*)&whiF[1 * 8192 + fo];
        f16x8 bl = *(const f16x8*)&wloF[1 * 8192 + fo];
        h1 = __builtin_amdgcn_mfma_f32_16x16x32_f16(ah, bh, h1, 0, 0, 0);
        l1 = __builtin_amdgcn_mfma_f32_16x16x32_f16(ah, bl, l1, 0, 0, 0);
      }
      {
        f16x8 bh = *(const f16x8*)&whiF[2 * 8192 + fo];
        f16x8 bl = *(const f16x8*)&wloF[2 * 8192 + fo];
        h2 = __builtin_amdgcn_mfma_f32_16x16x32_f16(ah, bh, h2, 0, 0, 0);
        l2 = __builtin_amdgcn_mfma_f32_16x16x32_f16(ah, bl, l2, 0, 0, 0);
      }
      {
        f16x8 bh = *(const f16x8*)&whiF[3 * 8192 + fo];
        f16x8 bl = *(const f16x8*)&wloF[3 * 8192 + fo];
        h3 = __builtin_amdgcn_mfma_f32_16x16x32_f16(ah, bh, h3, 0, 0, 0);
        l3 = __builtin_amdgcn_mfma_f32_16x16x32_f16(ah, bl, l3, 0, 0, 0);
      }
    }
    const float ls = 1.0f / 1024.0f;
    f32x4 acc0 = h0 + l0 * ls;
    f32x4 acc1 = h1 + l1 * ls;
    f32x4 acc2 = h2 + l2 * ls;
    f32x4 acc3 = h3 + l3 * ls;

    // ---- two-stage K-partial reduction in LDS ----
    const int rrow = m * 16 + lk * 4;
    if (ks < 2) {
      #pragma unroll
      for (int r = 0; r < 4; ++r) {
        gates2[ks][0][rrow + r][lm] = acc0[r];
        gates2[ks][1][rrow + r][lm] = acc1[r];
        gates2[ks][2][rrow + r][lm] = acc2[r];
        gates2[ks][3][rrow + r][lm] = acc3[r];
      }
    }
    __syncthreads();
    if (ks >= 2) {
      #pragma unroll
      for (int r = 0; r < 4; ++r) {
        gates2[ks - 2][0][rrow + r][lm] += acc0[r];
        gates2[ks - 2][1][rrow + r][lm] += acc1[r];
        gates2[ks - 2][2][rrow + r][lm] += acc2[r];
        gates2[ks - 2][3][rrow + r][lm] += acc3[r];
      }
    }
    __syncthreads();

    // ---- gate combine + direct coalesced fp16 h store (LLC write-through) ----
    {
      float xv0 = xs[cb][0], xv1 = xs[cb][1], xv2 = xs[cb][2];
      float pre[4];
      #pragma unroll
      for (int qq = 0; qq < 4; ++qq) {
        int r = qq * 16 + cj;
        pre[qq] = gates2[0][qq][cb][cj] + gates2[1][qq][cb][cj] + bsum[r]
                + xv0 * wih_s[r][0] + xv1 * wih_s[r][1] + xv2 * wih_s[r][2];
      }
      float ig = sigm(pre[0]), fg = sigm(pre[1]);
      float gg = tanhx(pre[2]), og = sigm(pre[3]);
      c_state = fg * c_state + ig * gg;
      float hv = og * tanhx(c_state);
      unsigned uhw = f2h(hv);
      size_t ho = (size_t)(cur ^ 1) * Bsz * Hh + (size_t)(b0 + cb) * Hh + j0 + cj;
      asm volatile("global_store_short %0, %1, off sc0 sc1" :: "v"(hpl + ho), "v"(uhw));
    }

    group_barrier(flags, hb, tid, (unsigned)(t + 2));
    cur ^= 1;
  }

  // ---- epilogue: wgs hb==0 compute FC for their 32 batches ----
  if (hb == 0) {
    const u64* Hf = (const u64*)(hpl + (size_t)cur * Bsz * Hh);
    int b = tid >> 4, lj = tid & 15;
    float p = 0.0f;
    for (int jq = lj; jq < Hh / 4; jq += 16) {
      size_t o = (size_t)(b0 + b) * (Hh / 4) + jq;
      u64 uh = __hip_atomic_load(Hf + o, __ATOMIC_RELAXED, __HIP_MEMORY_SCOPE_AGENT);
      #pragma unroll
      for (int e = 0; e < 4; ++e)
        p += h2f((ushort)(uh >> (16 * e))) * fcw[4 * jq + e];
    }
    __syncthreads();
    ((float*)gates2)[tid] = p;
    __syncthreads();
    if (lj == 0) {
      float s = 0.0f;
      #pragma unroll
      for (int r = 0; r < 16; ++r) s += ((float*)gates2)[(b << 4) + r];
      out[b0 + b] = s + fcb[0];
    }
  }
}

extern "C" void kernel_launch(void* const* d_in, const int* in_sizes, int n_in,
                              void* d_out, int out_size, void* d_ws, size_t ws_size,
                              hipStream_t stream) {
  const float* x   = (const float*)d_in[0];
  const float* Wih = (const float*)d_in[1];
  const float* Whh = (const float*)d_in[2];
  const float* bih = (const float*)d_in[3];
  const float* bhh = (const float*)d_in[4];
  const float* fcw = (const float*)d_in[5];
  const float* fcb = (const float*)d_in[6];
  float* out = (float*)d_out;
  char*  ws  = (char*)d_ws;

  hipLaunchKernelGGL(init_ws, dim3(1), dim3(CTRL_UINTS), 0, stream,
                     (unsigned*)(ws + BAR_OFF));
  hipLaunchKernelGGL(lstm_kernel, dim3(NWG), dim3(NTHR), 0, stream,
                     x, Wih, Whh, bih, bhh, fcw, fcb, out, ws);
}

// Round 15
// 1834.408 us; speedup vs baseline: 5.1653x; 5.1653x over previous
//
#include <hip/hip_runtime.h>

// SimpleLSTM B=256, T=512, I=3, H=512. out = fc(h_T).
// R15 = R13 numerics/memops (known-pass 1.93ms, absmax 2.44e-4) with the
// full per-step barrier replaced by a DATAFLOW PIPELINE:
//  - h triple-buffered (h_t in buf[t%3]) -> 2-step WAR slack.
//  - per-quarter read gates: wave (m,ks) polls only its 8 producer flags
//    (hb in [8ks,8ks+8)) >= t+1, then loads/MFMAs while others still wait.
//  - WAR gate (all 32 flags >= t, slack-2, ~always instant) by wave 0,
//    ordered before h-stores via the reduction syncthreads.
//  - end of step: drain + syncthreads + tid0 stores flag = t+2. No exit wait.
//  - anti-contention (R9 lesson): flags at 64B stride (one line each),
//    only lanes<8 (quarter) / lanes<32 (wave0 merged) issue poll loads,
//    s_sleep(2) pacing, poll-first.
// R14 lesson: NO cache-control fences; all cross-wg data sc0sc1 at LLC.

#define Hh   512
#define Bsz  256
#define Tt   512

#define MB   32
#define HS   16
#define NROW 64
#define NTHR 512
#define NWG  256

typedef float    f32x4 __attribute__((ext_vector_type(4)));
typedef _Float16 f16x8 __attribute__((ext_vector_type(8)));
typedef unsigned long long u64;

#define PLANE_ELE (Bsz * Hh)                 // 131072 fp16 per plane
#define PLANES   3
#define BAR_OFF  (PLANES * PLANE_ELE * 2)    // 768 KB
#define CTRL_UINTS 4096                      // 8 groups x 32 flags x 16-uint stride

__device__ __forceinline__ float sigm(float v)  { return 1.0f / (1.0f + __expf(-v)); }
__device__ __forceinline__ float tanhx(float v) { return 2.0f / (1.0f + __expf(-2.0f * v)) - 1.0f; }

__device__ __forceinline__ ushort f2h(float f) {
  return __builtin_bit_cast(ushort, (_Float16)f);
}
__device__ __forceinline__ float h2f(ushort u) {
  return (float)__builtin_bit_cast(_Float16, u);
}

#define GLOAD(dst, base, imm)                                            \
  asm volatile("global_load_dwordx4 %0, %1, off offset:%c2 sc0 sc1"      \
               : "=v"(dst) : "v"(base), "i"(imm))

__global__ void init_ws(unsigned* ctrl) {
  for (int i = threadIdx.x; i < CTRL_UINTS; i += NTHR) ctrl[i] = 0u;
}

__global__ __launch_bounds__(NTHR, 2)
void lstm_kernel(const float* __restrict__ x,   const float* __restrict__ Wih,
                 const float* __restrict__ Whh, const float* __restrict__ bih,
                 const float* __restrict__ bhh, const float* __restrict__ fcw,
                 const float* __restrict__ fcb, float* __restrict__ out,
                 char* __restrict__ ws)
{
  const int tid = threadIdx.x;
  const int wg  = blockIdx.x;
  const int bb  = wg & 7;
  const int hb  = wg >> 3;
  const int j0  = hb * HS;
  const int b0  = bb * MB;

  ushort*   hpl   = (ushort*)ws;                       // fp16 h planes [3][256][512]
  unsigned* flags = (unsigned*)(ws + BAR_OFF) + bb * 512;  // flag(hb) at [hb*16]

  __shared__ ushort whiF[4 * 16 * 64 * 8];   // 64 KB: f16(W)
  __shared__ ushort wloF[4 * 16 * 64 * 8];   // 64 KB: f16((W - hi) * 1024)
  __shared__ float  gates2[2][4][MB][20];
  __shared__ float  wih_s[NROW][3];
  __shared__ float  bsum[NROW];
  __shared__ float  xs[MB][3];

  if (tid < NROW) {
    int qq = tid >> 4, jj = tid & 15;
    int grow = qq * Hh + j0 + jj;
    wih_s[tid][0] = Wih[grow * 3 + 0];
    wih_s[tid][1] = Wih[grow * 3 + 1];
    wih_s[tid][2] = Wih[grow * 3 + 2];
    bsum[tid] = bih[grow] + bhh[grow];
  }

  for (int idx = tid; idx < NROW * 64; idx += NTHR) {
    int row = idx >> 6, seg = idx & 63;
    int qq = row >> 4, jj = row & 15;
    const float* src = Whh + (size_t)(qq * Hh + j0 + jj) * Hh + seg * 8;
    float4 w0 = *(const float4*)(src);
    float4 w1 = *(const float4*)(src + 4);
    float wv[8] = {w0.x, w0.y, w0.z, w0.w, w1.x, w1.y, w1.z, w1.w};
    unsigned uhi[4], ulo[4];
    #pragma unroll
    for (int p = 0; p < 4; ++p) {
      ushort h0 = f2h(wv[2*p]);
      ushort h1 = f2h(wv[2*p+1]);
      ushort l0 = f2h((wv[2*p]   - h2f(h0)) * 1024.0f);
      ushort l1 = f2h((wv[2*p+1] - h2f(h1)) * 1024.0f);
      uhi[p] = (unsigned)h0 | ((unsigned)h1 << 16);
      ulo[p] = (unsigned)l0 | ((unsigned)l1 << 16);
    }
    int kblk = seg >> 2, lkk = seg & 3;
    int dst = ((qq * 16 + kblk) * 64 + lkk * 16 + jj) * 8;
    *(uint4*)&whiF[dst] = make_uint4(uhi[0], uhi[1], uhi[2], uhi[3]);
    *(uint4*)&wloF[dst] = make_uint4(ulo[0], ulo[1], ulo[2], ulo[3]);
  }

  // ---- zero h_0 slice in plane 0, publish flag = 1 ----
  {
    int b = tid >> 4, jj = tid & 15;
    size_t o = (size_t)(b0 + b) * Hh + j0 + jj;
    __hip_atomic_store(&hpl[o], (ushort)0, __ATOMIC_RELAXED, __HIP_MEMORY_SCOPE_AGENT);
  }
  asm volatile("s_waitcnt vmcnt(0)" ::: "memory");
  __syncthreads();
  if (tid == 0) {
    unsigned fv = 1u;
    asm volatile("global_store_dword %0, %1, off sc0 sc1"
                 :: "v"(flags + hb * 16), "v"(fv) : "memory");
  }

  const int l   = tid & 63;
  const int wid = tid >> 6;
  const int m   = wid >> 2;            // batch half (0..1)
  const int ks  = wid & 3;             // K quarter (0..3)
  const int lm  = l & 15;
  const int lk  = l >> 4;              // 0..3

  const size_t aoff = (size_t)(b0 + m * 16 + lm) * Hh + ks * 128 + lk * 8;
  const int    wq0  = ks * 2048 + l * 8;

  const int cb = tid >> 4;
  const int cj = tid & 15;
  float c_state = 0.0f;

  int rd = 0, wr = 1;
  for (int t = 0; t < Tt; ++t) {
    // ---- gates: wave0 = merged WAR(all>=t) + own quarter(>=t+1);
    //      other waves = own-quarter only ----
    {
      const unsigned tq = (unsigned)(t + 1);
      const unsigned tw = (unsigned)t;
      if (wid == 0) {
        unsigned v = 0xFFFFFFFFu;
        const unsigned* fp = flags + (l & 31) * 16;
        for (;;) {
          if (l < 32)
            asm volatile("global_load_dword %0, %1, off sc0 sc1" : "=v"(v) : "v"(fp) : "memory");
          asm volatile("s_waitcnt vmcnt(0)" ::: "memory");
          unsigned need = ((l & 31) < 8) ? tq : tw;
          if (__all((int)(v >= need))) break;
          __builtin_amdgcn_s_sleep(2);
        }
      } else {
        unsigned v = 0xFFFFFFFFu;
        const unsigned* fp = flags + (ks * 8 + (l & 7)) * 16;
        for (;;) {
          if (l < 8)
            asm volatile("global_load_dword %0, %1, off sc0 sc1" : "=v"(v) : "v"(fp) : "memory");
          asm volatile("s_waitcnt vmcnt(0)" ::: "memory");
          if (__all((int)(v >= tq))) break;
          __builtin_amdgcn_s_sleep(2);
        }
      }
    }

    if (tid < MB * 3) {
      int b = tid / 3, ii = tid - b * 3;
      xs[b][ii] = x[(size_t)(b0 + b) * (Tt * 3) + t * 3 + ii];
    }

    // ---- 4 pipelined A loads (own K-quarter of h_t, fp16, LLC) ----
    const char* pH = (const char*)(hpl + (size_t)rd * PLANE_ELE + aoff);
    f32x4 AH[4];
    GLOAD(AH[0], pH, 0);  GLOAD(AH[1], pH, 64);  GLOAD(AH[2], pH, 128); GLOAD(AH[3], pH, 192);
    asm volatile("s_waitcnt vmcnt(0)" ::: "memory");
    __builtin_amdgcn_sched_barrier(0);

    // ---- 4 quadrants x 4 k-blocks x 2 terms = 32 MFMAs ----
    f32x4 h0 = {0,0,0,0}, h1 = {0,0,0,0}, h2 = {0,0,0,0}, h3 = {0,0,0,0};
    f32x4 l0 = {0,0,0,0}, l1 = {0,0,0,0}, l2 = {0,0,0,0}, l3 = {0,0,0,0};
    #pragma unroll
    for (int u = 0; u < 4; ++u) {
      f16x8 ah = __builtin_bit_cast(f16x8, AH[u]);
      const int fo = wq0 + u * 512;
      {
        f16x8 bh = *(const f16x8*)&whiF[0 * 8192 + fo];
        f16x8 bl = *(const f16x8*)&wloF[0 * 8192 + fo];
        h0 = __builtin_amdgcn_mfma_f32_16x16x32_f16(ah, bh, h0, 0, 0, 0);
        l0 = __builtin_amdgcn_mfma_f32_16x16x32_f16(ah, bl, l0, 0, 0, 0);
      }
      {
        f16x8 bh = *(const f16x8*)&whiF[1 * 8192 + fo];
        f16x8 bl = *(const f16x8*)&wloF[1 * 8192 + fo];
        h1 = __builtin_amdgcn_mfma_f32_16x16x32_f16(ah, bh, h1, 0, 0, 0);
        l1 = __builtin_amdgcn_mfma_f32_16x16x32_f16(ah, bl, l1, 0, 0, 0);
      }
      {
        f16x8 bh = *(const f16x8*)&whiF[2 * 8192 + fo];
        f16x8 bl = *(const f16x8*)&wloF[2 * 8192 + fo];
        h2 = __builtin_amdgcn_mfma_f32_16x16x32_f16(ah, bh, h2, 0, 0, 0);
        l2 = __builtin_amdgcn_mfma_f32_16x16x32_f16(ah, bl, l2, 0, 0, 0);
      }
      {
        f16x8 bh = *(const f16x8*)&whiF[3 * 8192 + fo];
        f16x8 bl = *(const f16x8*)&wloF[3 * 8192 + fo];
        h3 = __builtin_amdgcn_mfma_f32_16x16x32_f16(ah, bh, h3, 0, 0, 0);
        l3 = __builtin_amdgcn_mfma_f32_16x16x32_f16(ah, bl, l3, 0, 0, 0);
      }
    }
    const float ls = 1.0f / 1024.0f;
    f32x4 acc0 = h0 + l0 * ls;
    f32x4 acc1 = h1 + l1 * ls;
    f32x4 acc2 = h2 + l2 * ls;
    f32x4 acc3 = h3 + l3 * ls;

    // ---- two-stage K-partial reduction in LDS ----
    const int rrow = m * 16 + lk * 4;
    if (ks < 2) {
      #pragma unroll
      for (int r = 0; r < 4; ++r) {
        gates2[ks][0][rrow + r][lm] = acc0[r];
        gates2[ks][1][rrow + r][lm] = acc1[r];
        gates2[ks][2][rrow + r][lm] = acc2[r];
        gates2[ks][3][rrow + r][lm] = acc3[r];
      }
    }
    __syncthreads();
    if (ks >= 2) {
      #pragma unroll
      for (int r = 0; r < 4; ++r) {
        gates2[ks - 2][0][rrow + r][lm] += acc0[r];
        gates2[ks - 2][1][rrow + r][lm] += acc1[r];
        gates2[ks - 2][2][rrow + r][lm] += acc2[r];
        gates2[ks - 2][3][rrow + r][lm] += acc3[r];
      }
    }
    __syncthreads();   // also orders wave0's WAR gate before all h-stores

    // ---- gate combine + direct fp16 h store into plane wr ----
    {
      float xv0 = xs[cb][0], xv1 = xs[cb][1], xv2 = xs[cb][2];
      float pre[4];
      #pragma unroll
      for (int qq = 0; qq < 4; ++qq) {
        int r = qq * 16 + cj;
        pre[qq] = gates2[0][qq][cb][cj] + gates2[1][qq][cb][cj] + bsum[r]
                + xv0 * wih_s[r][0] + xv1 * wih_s[r][1] + xv2 * wih_s[r][2];
      }
      float ig = sigm(pre[0]), fg = sigm(pre[1]);
      float gg = tanhx(pre[2]), og = sigm(pre[3]);
      c_state = fg * c_state + ig * gg;
      float hv = og * tanhx(c_state);
      unsigned uhw = f2h(hv);
      size_t ho = (size_t)wr * PLANE_ELE + (size_t)(b0 + cb) * Hh + j0 + cj;
      asm volatile("global_store_short %0, %1, off sc0 sc1" :: "v"(hpl + ho), "v"(uhw));
    }

    // ---- end of step: drain own stores, converge, publish flag ----
    asm volatile("s_waitcnt vmcnt(0)" ::: "memory");
    __syncthreads();
    if (tid == 0) {
      unsigned fv = (unsigned)(t + 2);
      asm volatile("global_store_dword %0, %1, off sc0 sc1"
                   :: "v"(flags + hb * 16), "v"(fv) : "memory");
    }

    rd = wr;
    wr = (wr == 2) ? 0 : wr + 1;
  }

  // ---- epilogue: wgs hb==0 wait for all wgs' final h, then FC ----
  if (hb == 0) {
    if (tid < 64) {
      unsigned v = 0xFFFFFFFFu;
      const unsigned* fp = flags + (l & 31) * 16;
      const unsigned tgt = (unsigned)(Tt + 1);
      for (;;) {
        if (l < 32)
          asm volatile("global_load_dword %0, %1, off sc0 sc1" : "=v"(v) : "v"(fp) : "memory");
        asm volatile("s_waitcnt vmcnt(0)" ::: "memory");
        if (__all((int)(v >= tgt))) break;
        __builtin_amdgcn_s_sleep(2);
      }
    }
    __syncthreads();

    const u64* Hf = (const u64*)(hpl + (size_t)rd * PLANE_ELE);
    int b = tid >> 4, lj = tid & 15;
    float p = 0.0f;
    for (int jq = lj; jq < Hh / 4; jq += 16) {
      size_t o = (size_t)(b0 + b) * (Hh / 4) + jq;
      u64 uh = __hip_atomic_load(Hf + o, __ATOMIC_RELAXED, __HIP_MEMORY_SCOPE_AGENT);
      #pragma unroll
      for (int e = 0; e < 4; ++e)
        p += h2f((ushort)(uh >> (16 * e))) * fcw[4 * jq + e];
    }
    __syncthreads();
    ((float*)gates2)[tid] = p;
    __syncthreads();
    if (lj == 0) {
      float s = 0.0f;
      #pragma unroll
      for (int r = 0; r < 16; ++r) s += ((float*)gates2)[(b << 4) + r];
      out[b0 + b] = s + fcb[0];
    }
  }
}

extern "C" void kernel_launch(void* const* d_in, const int* in_sizes, int n_in,
                              void* d_out, int out_size, void* d_ws, size_t ws_size,
                              hipStream_t stream) {
  const float* x   = (const float*)d_in[0];
  const float* Wih = (const float*)d_in[1];
  const float* Whh = (const float*)d_in[2];
  const float* bih = (const float*)d_in[3];
  const float* bhh = (const float*)d_in[4];
  const float* fcw = (const float*)d_in[5];
  const float* fcb = (const float*)d_in[6];
  float* out = (float*)d_out;
  char*  ws  = (char*)d_ws;

  hipLaunchKernelGGL(init_ws, dim3(1), dim3(NTHR), 0, stream,
                     (unsigned*)(ws + BAR_OFF));
  hipLaunchKernelGGL(lstm_kernel, dim3(NWG), dim3(NTHR), 0, stream,
                     x, Wih, Whh, bih, bhh, fcw, fcb, out, ws);
}

// Round 16
// 1698.157 us; speedup vs baseline: 5.5797x; 1.0802x over previous
//
#include <hip/hip_runtime.h>

// SimpleLSTM B=256, T=512, I=3, H=512. out = fc(h_T).
// R16: cut the UC/LLC A-read redundancy 2x by fattening wgs in hidden.
//  - 256 wgs x 512 thr: bb = wg&15 (16 batch groups x 16 batches),
//    hb = wg>>4 (16 hidden blocks x HS=32). NROW = 128 gate rows/wg.
//  - 8 waves = 8 K-EIGHTHS (64 k each). Each wave: all 128 rows over its
//    disjoint eighth -> wg reads 16KB/step (was 32KB) -> 4MB/step chip.
//  - W in REGISTERS (single-plane f16, 16 frags = 64 VGPR/lane); LDS ~37KB.
//    W-f16-only error ~4e-5 rms (vs h-quant 2.4e-4) -- budget OK.
//  - 4-buffer LDS reduction (ks<4 write, ks>=4 add), 2 syncthreads.
//  - R15-verified dataflow protocol verbatim: triple-buffered h planes,
//    per-wave producer gates (2 flags: hb = ks*2, ks*2+1), wave0 merged
//    WAR gate (all 16 >= t), publish t+2, no exit barrier.
// R14 lesson: no cache fences; all cross-wg data sc0sc1 at LLC.

#define Hh   512
#define Bsz  256
#define Tt   512

#define MB   16     // batches per group
#define HS   32     // hidden per wg
#define NROW 128    // gate rows per wg
#define NTHR 512
#define NWG  256

typedef float    f32x4 __attribute__((ext_vector_type(4)));
typedef _Float16 f16x8 __attribute__((ext_vector_type(8)));
typedef unsigned long long u64;

#define PLANE_ELE (Bsz * Hh)
#define PLANES   3
#define BAR_OFF  (PLANES * PLANE_ELE * 2)    // 768 KB
#define CTRL_UINTS 4096                      // 16 groups x 16 flags x 16-uint stride

__device__ __forceinline__ float sigm(float v)  { return 1.0f / (1.0f + __expf(-v)); }
__device__ __forceinline__ float tanhx(float v) { return 2.0f / (1.0f + __expf(-2.0f * v)) - 1.0f; }

__device__ __forceinline__ float h2f(ushort u) {
  return (float)__builtin_bit_cast(_Float16, u);
}
__device__ __forceinline__ ushort f2h(float f) {
  return __builtin_bit_cast(ushort, (_Float16)f);
}

#define GLOAD(dst, base, imm)                                            \
  asm volatile("global_load_dwordx4 %0, %1, off offset:%c2 sc0 sc1"      \
               : "=v"(dst) : "v"(base), "i"(imm))

__global__ void init_ws(unsigned* ctrl) {
  for (int i = threadIdx.x; i < CTRL_UINTS; i += NTHR) ctrl[i] = 0u;
}

__global__ __launch_bounds__(NTHR, 2)
void lstm_kernel(const float* __restrict__ x,   const float* __restrict__ Wih,
                 const float* __restrict__ Whh, const float* __restrict__ bih,
                 const float* __restrict__ bhh, const float* __restrict__ fcw,
                 const float* __restrict__ fcb, float* __restrict__ out,
                 char* __restrict__ ws)
{
  const int tid = threadIdx.x;
  const int wg  = blockIdx.x;
  const int bb  = wg & 15;             // batch group (16 batches)
  const int hb  = wg >> 4;             // hidden block (32 hidden)
  const int j0  = hb * HS;
  const int b0  = bb * MB;

  ushort*   hpl   = (ushort*)ws;                           // [3][256][512] f16
  unsigned* flags = (unsigned*)(ws + BAR_OFF) + bb * 256;  // flag(hb) at [hb*16]

  __shared__ float gates2[4][NROW][17];    // K-partials (4 bufs), ~34.8 KB
  __shared__ float wih_s[NROW][3];
  __shared__ float bsum[NROW];
  __shared__ float xs[MB][3];

  if (tid < NROW) {
    int qq = tid >> 5, jj = tid & 31;
    int grow = qq * Hh + j0 + jj;
    wih_s[tid][0] = Wih[grow * 3 + 0];
    wih_s[tid][1] = Wih[grow * 3 + 1];
    wih_s[tid][2] = Wih[grow * 3 + 2];
    bsum[tid] = bih[grow] + bhh[grow];
  }

  const int l   = tid & 63;
  const int ks  = tid >> 6;            // K-eighth (0..7), 64 k each
  const int lm  = l & 15;
  const int lk  = l >> 4;              // 0..3

  // ---- W fragments -> registers (single-plane f16) ----
  // wfrag[rb][kb]: B-operand for gate rows rb*16..+16, k-block ks*2+kb.
  // lane (lk,lm): col(row) = rb*16+lm, k = (ks*2+kb)*32 + lk*8 .. +8.
  f16x8 wfrag[8][2];
  #pragma unroll
  for (int rb = 0; rb < 8; ++rb) {
    #pragma unroll
    for (int kb = 0; kb < 2; ++kb) {
      int rr = rb * 16 + lm;
      int grow = (rr >> 5) * Hh + j0 + (rr & 31);
      int col = (ks * 2 + kb) * 32 + lk * 8;
      const float* wsrc = Whh + (size_t)grow * Hh + col;
      float4 wa = *(const float4*)(wsrc);
      float4 wb = *(const float4*)(wsrc + 4);
      f16x8 f;
      f[0] = (_Float16)wa.x; f[1] = (_Float16)wa.y;
      f[2] = (_Float16)wa.z; f[3] = (_Float16)wa.w;
      f[4] = (_Float16)wb.x; f[5] = (_Float16)wb.y;
      f[6] = (_Float16)wb.z; f[7] = (_Float16)wb.w;
      wfrag[rb][kb] = f;
    }
  }

  // ---- zero h_0 slice in plane 0, publish flag = 1 ----
  {
    int cb0 = tid >> 5, cj0 = tid & 31;
    size_t o = (size_t)(b0 + cb0) * Hh + j0 + cj0;
    __hip_atomic_store(&hpl[o], (ushort)0, __ATOMIC_RELAXED, __HIP_MEMORY_SCOPE_AGENT);
  }
  asm volatile("s_waitcnt vmcnt(0)" ::: "memory");
  __syncthreads();
  if (tid == 0) {
    unsigned fv = 1u;
    asm volatile("global_store_dword %0, %1, off sc0 sc1"
                 :: "v"(flags + hb * 16), "v"(fv) : "memory");
  }

  const size_t aoff = (size_t)(b0 + lm) * Hh + ks * 64 + lk * 8;

  const int cb = tid >> 5;             // combine batch (0..15)
  const int cj = tid & 31;             // combine hidden (0..31)
  float c_state = 0.0f;

  int rd = 0, wr = 1;
  for (int t = 0; t < Tt; ++t) {
    // ---- gates (R15-verified protocol): wave0 merged WAR + own producers;
    //      other waves: own 2 producers (hb = ks*2, ks*2+1) >= t+1 ----
    {
      const unsigned tq = (unsigned)(t + 1);
      const unsigned tw = (unsigned)t;
      if (ks == 0) {
        unsigned v = 0xFFFFFFFFu;
        const unsigned* fp = flags + (l & 15) * 16;
        for (;;) {
          if (l < 16)
            asm volatile("global_load_dword %0, %1, off sc0 sc1" : "=v"(v) : "v"(fp) : "memory");
          asm volatile("s_waitcnt vmcnt(0)" ::: "memory");
          unsigned need = ((l & 15) < 2) ? tq : tw;
          if (__all((int)(v >= need))) break;
          __builtin_amdgcn_s_sleep(2);
        }
      } else {
        unsigned v = 0xFFFFFFFFu;
        const unsigned* fp = flags + (ks * 2 + (l & 1)) * 16;
        for (;;) {
          if (l < 2)
            asm volatile("global_load_dword %0, %1, off sc0 sc1" : "=v"(v) : "v"(fp) : "memory");
          asm volatile("s_waitcnt vmcnt(0)" ::: "memory");
          if (__all((int)(v >= tq))) break;
          __builtin_amdgcn_s_sleep(2);
        }
      }
    }

    if (tid < MB * 3) {
      int b = tid / 3, ii = tid - b * 3;
      xs[b][ii] = x[(size_t)(b0 + b) * (Tt * 3) + t * 3 + ii];
    }

    // ---- 2 pipelined A loads (own K-eighth of h_t) ----
    const char* pH = (const char*)(hpl + (size_t)rd * PLANE_ELE + aoff);
    f32x4 AH[2];
    GLOAD(AH[0], pH, 0);  GLOAD(AH[1], pH, 64);
    asm volatile("s_waitcnt vmcnt(0)" ::: "memory");
    __builtin_amdgcn_sched_barrier(0);

    // ---- 8 row-blocks x 2 k-blocks = 16 MFMAs ----
    f32x4 acc[8];
    #pragma unroll
    for (int rb = 0; rb < 8; ++rb) acc[rb] = (f32x4){0.f, 0.f, 0.f, 0.f};
    #pragma unroll
    for (int kb = 0; kb < 2; ++kb) {
      f16x8 ah = __builtin_bit_cast(f16x8, AH[kb]);
      #pragma unroll
      for (int rb = 0; rb < 8; ++rb)
        acc[rb] = __builtin_amdgcn_mfma_f32_16x16x32_f16(ah, wfrag[rb][kb], acc[rb], 0, 0, 0);
    }

    // ---- 4-buffer K-partial reduction in LDS ----
    // C mapping: batch = lk*4 + r, gate row = rb*16 + lm.
    if (ks < 4) {
      #pragma unroll
      for (int rb = 0; rb < 8; ++rb)
        #pragma unroll
        for (int r = 0; r < 4; ++r)
          gates2[ks][rb * 16 + lm][lk * 4 + r] = acc[rb][r];
    }
    __syncthreads();
    if (ks >= 4) {
      #pragma unroll
      for (int rb = 0; rb < 8; ++rb)
        #pragma unroll
        for (int r = 0; r < 4; ++r)
          gates2[ks - 4][rb * 16 + lm][lk * 4 + r] += acc[rb][r];
    }
    __syncthreads();   // also orders wave0's WAR gate before all h stores

    // ---- gate combine + direct fp16 h store into plane wr ----
    {
      float xv0 = xs[cb][0], xv1 = xs[cb][1], xv2 = xs[cb][2];
      float pre[4];
      #pragma unroll
      for (int qq = 0; qq < 4; ++qq) {
        int rrq = qq * 32 + cj;
        pre[qq] = gates2[0][rrq][cb] + gates2[1][rrq][cb]
                + gates2[2][rrq][cb] + gates2[3][rrq][cb] + bsum[rrq]
                + xv0 * wih_s[rrq][0] + xv1 * wih_s[rrq][1] + xv2 * wih_s[rrq][2];
      }
      float ig = sigm(pre[0]), fg = sigm(pre[1]);
      float gg = tanhx(pre[2]), og = sigm(pre[3]);
      c_state = fg * c_state + ig * gg;
      float hv = og * tanhx(c_state);
      unsigned uhw = f2h(hv);
      size_t ho = (size_t)wr * PLANE_ELE + (size_t)(b0 + cb) * Hh + j0 + cj;
      asm volatile("global_store_short %0, %1, off sc0 sc1" :: "v"(hpl + ho), "v"(uhw));
    }

    // ---- end of step: drain own stores, converge, publish flag ----
    asm volatile("s_waitcnt vmcnt(0)" ::: "memory");
    __syncthreads();
    if (tid == 0) {
      unsigned fv = (unsigned)(t + 2);
      asm volatile("global_store_dword %0, %1, off sc0 sc1"
                   :: "v"(flags + hb * 16), "v"(fv) : "memory");
    }

    rd = wr;
    wr = (wr == 2) ? 0 : wr + 1;
  }

  // ---- epilogue: hb==0 wgs wait for all final h, then FC (16 batches) ----
  if (hb == 0) {
    if (tid < 64) {
      unsigned v = 0xFFFFFFFFu;
      const unsigned* fp = flags + (l & 15) * 16;
      const unsigned tgt = (unsigned)(Tt + 1);
      for (;;) {
        if (l < 16)
          asm volatile("global_load_dword %0, %1, off sc0 sc1" : "=v"(v) : "v"(fp) : "memory");
        asm volatile("s_waitcnt vmcnt(0)" ::: "memory");
        if (__all((int)(v >= tgt))) break;
        __builtin_amdgcn_s_sleep(2);
      }
    }
    __syncthreads();

    const u64* Hf = (const u64*)(hpl + (size_t)rd * PLANE_ELE);
    int b = tid >> 5, lj = tid & 31;
    float p = 0.0f;
    for (int jq = lj; jq < Hh / 4; jq += 32) {
      size_t o = (size_t)(b0 + b) * (Hh / 4) + jq;
      u64 uh = __hip_atomic_load(Hf + o, __ATOMIC_RELAXED, __HIP_MEMORY_SCOPE_AGENT);
      #pragma unroll
      for (int e = 0; e < 4; ++e)
        p += h2f((ushort)(uh >> (16 * e))) * fcw[4 * jq + e];
    }
    __syncthreads();
    ((float*)gates2)[tid] = p;
    __syncthreads();
    if (lj == 0) {
      float s = 0.0f;
      #pragma unroll
      for (int r = 0; r < 32; ++r) s += ((float*)gates2)[(b << 5) + r];
      out[b0 + b] = s + fcb[0];
    }
  }
}

extern "C" void kernel_launch(void* const* d_in, const int* in_sizes, int n_in,
                              void* d_out, int out_size, void* d_ws, size_t ws_size,
                              hipStream_t stream) {
  const float* x   = (const float*)d_in[0];
  const float* Wih = (const float*)d_in[1];
  const float* Whh = (const float*)d_in[2];
  const float* bih = (const float*)d_in[3];
  const float* bhh = (const float*)d_in[4];
  const float* fcw = (const float*)d_in[5];
  const float* fcb = (const float*)d_in[6];
  float* out = (float*)d_out;
  char*  ws  = (char*)d_ws;

  hipLaunchKernelGGL(init_ws, dim3(1), dim3(NTHR), 0, stream,
                     (unsigned*)(ws + BAR_OFF));
  hipLaunchKernelGGL(lstm_kernel, dim3(NWG), dim3(NTHR), 0, stream,
                     x, Wih, Whh, bih, bhh, fcw, fcb, out, ws);
}